// Round 1
// baseline (207.181 us; speedup 1.0000x reference)
//
#include <hip/hip_runtime.h>
#include <hip/hip_bf16.h>

// GraphSage on MI355X.
// Pipeline (all bf16 intermediates, fp32 accumulation):
//   K0: cast features fp32 -> X1[:,0:128] bf16               (reads 51MB, writes 25MB)
//   K1: X1[:,128:256] = mean of 16 neighbor self-rows (bf16)  (gather 410MB, L3-served)
//   G1: h1[N,128] bf16 = X1[N,256] @ w1 (MFMA 16x16x32 bf16)
//   K3: X2[B,256] = [h1[node] | mean h1[nbr]]                 (gather ~36MB)
//   G2: out[B,128] fp32 = X2 @ w2 (MFMA)

#define N_NODES 100000
#define DEG     16
#define FDIM    128
#define HDIM    128
#define ODIM    128
#define B_NODES 8192

typedef __attribute__((ext_vector_type(8))) short bf16x8;
typedef __attribute__((ext_vector_type(4))) float f32x4;

static __device__ __forceinline__ unsigned short f2bf(float f) {
    union { float f; unsigned u; } v; v.f = f;
    unsigned r = v.u + 0x7fff + ((v.u >> 16) & 1);   // round-to-nearest-even
    return (unsigned short)(r >> 16);
}
static __device__ __forceinline__ float bf2f(unsigned short b) {
    union { unsigned u; float f; } v; v.u = ((unsigned)b) << 16;
    return v.f;
}

// K0: cast features -> self half of X1 (row stride 256)
__global__ void k0_cast(const float* __restrict__ feat, unsigned short* __restrict__ X1) {
    int t = blockIdx.x * blockDim.x + threadIdx.x;
    long e = (long)t * 4;
    if (e >= (long)N_NODES * FDIM) return;
    float4 v = *(const float4*)(feat + e);
    int i = (int)(e >> 7), j = (int)(e & 127);
    ushort4 o;
    o.x = f2bf(v.x); o.y = f2bf(v.y); o.z = f2bf(v.z); o.w = f2bf(v.w);
    *(ushort4*)(X1 + i * 256 + j) = o;
}

// K1: agg half of X1 = mean over 16 neighbors of their self half (bf16 gather).
// 64 threads per node, each thread owns 2 columns.
__global__ void k1_agg(const int* __restrict__ nbr, unsigned short* __restrict__ X1) {
    int node = blockIdx.x * 4 + (threadIdx.x >> 6);
    if (node >= N_NODES) return;
    int j = (threadIdx.x & 63) * 2;
    const int* idx = nbr + node * DEG;
    float s0 = 0.f, s1 = 0.f;
#pragma unroll
    for (int d = 0; d < DEG; ++d) {
        int nb = idx[d];
        ushort2 v = *(const ushort2*)(X1 + nb * 256 + j);
        s0 += bf2f(v.x); s1 += bf2f(v.y);
    }
    ushort2 o;
    o.x = f2bf(s0 * (1.f / 16.f));
    o.y = f2bf(s1 * (1.f / 16.f));
    *(ushort2*)(X1 + node * 256 + 128 + j) = o;
}

// K3: X2[b] = [h1[nodes[b]] | mean_d h1[nbr[nodes[b]][d]]]
__global__ void k3_gather(const int* __restrict__ nbr, const int* __restrict__ nodes,
                          const unsigned short* __restrict__ h1,
                          unsigned short* __restrict__ X2) {
    int b = blockIdx.x * 4 + (threadIdx.x >> 6);
    if (b >= B_NODES) return;
    int j = (threadIdx.x & 63) * 2;
    int node = nodes[b];
    ushort2 sv = *(const ushort2*)(h1 + node * HDIM + j);
    *(ushort2*)(X2 + b * 256 + j) = sv;
    const int* idx = nbr + node * DEG;
    float s0 = 0.f, s1 = 0.f;
#pragma unroll
    for (int d = 0; d < DEG; ++d) {
        int nb = idx[d];
        ushort2 v = *(const ushort2*)(h1 + nb * HDIM + j);
        s0 += bf2f(v.x); s1 += bf2f(v.y);
    }
    ushort2 o;
    o.x = f2bf(s0 * (1.f / 16.f));
    o.y = f2bf(s1 * (1.f / 16.f));
    *(ushort2*)(X2 + b * 256 + 128 + j) = o;
}

// GEMM: Out[M,128] = X[M,256](bf16) @ W[256,128](fp32, cast to bf16 in LDS).
// Block: 256 threads (4 waves), 128 rows of output per block.
// wT[n][k] transposed in LDS (stride 264 bf16 -> 528B rows, 16B-aligned, ~2-way banks).
// A streamed in K=32 chunks (stride 40 bf16 -> 80B rows, 16B-aligned).
template <bool OUT_F32>
__global__ __launch_bounds__(256)
void gemm_kernel(const unsigned short* __restrict__ X, const float* __restrict__ W,
                 void* __restrict__ Out, int M) {
    __shared__ unsigned short wT[128][264];
    __shared__ unsigned short At[128][40];
    const int t = threadIdx.x;

    // Load W (fp32 [256,128] row-major) -> wT bf16 [n][k]
    for (int e = t; e < 256 * 128; e += 256) {
        int k = e >> 7, n = e & 127;
        wT[n][k] = f2bf(W[e]);
    }

    const int row0 = blockIdx.x * 128;
    const int wave = t >> 6, lane = t & 63;
    const int m16 = lane & 15, quad = lane >> 4;

    f32x4 acc[2][8] = {};

    for (int kc = 0; kc < 8; ++kc) {
        const int kbase = kc * 32;
        __syncthreads();  // protects wT (first iter) and At reuse (later iters)
        // Stage A chunk: 128 rows x 32 k, 4096 bf16; 256 threads x 2 passes x 8 elems
        {
            int lin = t * 8;
#pragma unroll
            for (int p = 0; p < 2; ++p) {
                int e = lin + p * 2048;
                int r = e >> 5, c = e & 31;
                int grow = row0 + r;
                ushort4 v0 = {0, 0, 0, 0}, v1 = {0, 0, 0, 0};
                if (grow < M) {
                    const unsigned short* src = X + grow * 256 + kbase + c;
                    v0 = *(const ushort4*)(src);
                    v1 = *(const ushort4*)(src + 4);
                }
                *(ushort4*)(&At[r][c]) = v0;
                *(ushort4*)(&At[r][c + 4]) = v1;
            }
        }
        __syncthreads();

        bf16x8 a[2], b[8];
#pragma unroll
        for (int mt = 0; mt < 2; ++mt) {
            int r = wave * 32 + mt * 16 + m16;
            a[mt] = *(const bf16x8*)(&At[r][quad * 8]);
        }
#pragma unroll
        for (int nt = 0; nt < 8; ++nt) {
            int n = nt * 16 + m16;
            b[nt] = *(const bf16x8*)(&wT[n][kbase + quad * 8]);
        }
#pragma unroll
        for (int mt = 0; mt < 2; ++mt)
#pragma unroll
            for (int nt = 0; nt < 8; ++nt)
                acc[mt][nt] = __builtin_amdgcn_mfma_f32_16x16x32_bf16(a[mt], b[nt], acc[mt][nt], 0, 0, 0);
    }

    // Epilogue: D row = (lane>>4)*4 + reg, col = (lane&15) [m89-verified layout]
#pragma unroll
    for (int mt = 0; mt < 2; ++mt) {
        int rbase = row0 + wave * 32 + mt * 16 + quad * 4;
#pragma unroll
        for (int reg = 0; reg < 4; ++reg) {
            int grow = rbase + reg;
            if (grow >= M) continue;
#pragma unroll
            for (int nt = 0; nt < 8; ++nt) {
                int col = nt * 16 + m16;
                float v = acc[mt][nt][reg];
                if (OUT_F32)
                    ((float*)Out)[grow * 128 + col] = v;
                else
                    ((unsigned short*)Out)[grow * 128 + col] = f2bf(v);
            }
        }
    }
}

extern "C" void kernel_launch(void* const* d_in, const int* in_sizes, int n_in,
                              void* d_out, int out_size, void* d_ws, size_t ws_size,
                              hipStream_t stream) {
    const float* feat  = (const float*)d_in[0];
    const float* w1    = (const float*)d_in[1];
    const float* w2    = (const float*)d_in[2];
    const int*   nbr   = (const int*)d_in[3];
    const int*   nodes = (const int*)d_in[4];
    float* out = (float*)d_out;

    char* ws = (char*)d_ws;
    unsigned short* X1 = (unsigned short*)ws;                           // N*256 bf16 = 51.2MB
    unsigned short* h1 = (unsigned short*)(ws + 51200000);              // N*128 bf16 = 25.6MB
    unsigned short* X2 = (unsigned short*)(ws + 51200000 + 25600000);   // B*256 bf16 = 4.2MB

    // K0: N*F/4 elems per thread-4 => 3.2M threads
    k0_cast<<<12500, 256, 0, stream>>>(feat, X1);
    // K1: 4 nodes per 256-thread block
    k1_agg<<<25000, 256, 0, stream>>>(nbr, X1);
    // G1: 128 rows/block
    gemm_kernel<false><<<(N_NODES + 127) / 128, 256, 0, stream>>>(X1, w1, (void*)h1, N_NODES);
    // K3: 4 batch nodes per block
    k3_gather<<<2048, 256, 0, stream>>>(nbr, nodes, h1, X2);
    // G2
    gemm_kernel<true><<<B_NODES / 128, 256, 0, stream>>>(X2, w2, (void*)out, B_NODES);
}

// Round 2
// 204.934 us; speedup vs baseline: 1.0110x; 1.0110x over previous
//
#include <hip/hip_runtime.h>

// GraphSage on MI355X — fused pipeline, 4 launches:
//   prep_feat: feat fp32 [N,128] -> fb bf16 [N,128] (dense gather source)
//   prep_w   : w1,w2 fp32 [256,128] -> w1T,w2T bf16 [n=128][k=256]
//   g1_fused : per 128-node block: gather+mean nbr fb rows -> LDS Agg,
//              MFMA (A self from global fb, A agg from LDS, B from global wT) -> h1 bf16
//   g2_fused : per 64-batch-node block: gather h1 self+nbr-mean -> LDS X2, MFMA -> out fp32

#define N_NODES 100000
#define DEG     16
#define FDIM    128
#define HDIM    128
#define B_NODES 8192

typedef __attribute__((ext_vector_type(8))) short bf16x8;
typedef __attribute__((ext_vector_type(8))) unsigned short u16x8;
typedef __attribute__((ext_vector_type(4))) float f32x4;

static __device__ __forceinline__ unsigned short f2bf(float f) {
    union { float f; unsigned u; } v; v.f = f;
    unsigned r = v.u + 0x7fff + ((v.u >> 16) & 1);   // round-to-nearest-even
    return (unsigned short)(r >> 16);
}
static __device__ __forceinline__ float bf2f(unsigned short b) {
    union { unsigned u; float f; } v; v.u = ((unsigned)b) << 16;
    return v.f;
}

__global__ void prep_feat(const float* __restrict__ feat, unsigned short* __restrict__ fb) {
    long e = ((long)blockIdx.x * 256 + threadIdx.x) * 8;
    if (e >= (long)N_NODES * FDIM) return;
    float4 v0 = *(const float4*)(feat + e);
    float4 v1 = *(const float4*)(feat + e + 4);
    u16x8 o;
    o[0] = f2bf(v0.x); o[1] = f2bf(v0.y); o[2] = f2bf(v0.z); o[3] = f2bf(v0.w);
    o[4] = f2bf(v1.x); o[5] = f2bf(v1.y); o[6] = f2bf(v1.z); o[7] = f2bf(v1.w);
    *(u16x8*)(fb + e) = o;
}

// w [256,128] fp32 row-major -> wT [128][256] bf16 (n-major). 16 blocks: 0-7 w1, 8-15 w2.
__global__ void prep_w(const float* __restrict__ w1, const float* __restrict__ w2,
                       unsigned short* __restrict__ w1T, unsigned short* __restrict__ w2T) {
    const float* w = (blockIdx.x < 8) ? w1 : w2;
    unsigned short* wT = (blockIdx.x < 8) ? w1T : w2T;
    int kb = (blockIdx.x & 7) * 32;
    int n = threadIdx.x & 127, dk = threadIdx.x >> 7;
#pragma unroll
    for (int i = 0; i < 16; ++i) {
        int k = kb + dk * 16 + i;
        wT[n * 256 + k] = f2bf(w[k * 128 + n]);   // read coalesced over n
    }
}

// Layer 1 fused: block = 256 threads, 128 output rows.
__global__ __launch_bounds__(256)
void g1_fused(const unsigned short* __restrict__ fb, const unsigned short* __restrict__ w1T,
              const int* __restrict__ nbr, unsigned short* __restrict__ h1) {
    __shared__ unsigned short Agg[128][136];   // stride 136 shorts = 272 B (16B-aligned, +4 banks/row)
    const int t = threadIdx.x, wave = t >> 6, lane = t & 63;
    const int m16 = lane & 15, quad = lane >> 4;
    const int row0 = blockIdx.x * 128;
    const int colb = m16 * 8;

    // Phase 1: neighbor mean -> Agg. Each quad of 16 lanes owns one node's row
    // (16 lanes x 16B = full 256B row per load). Wave covers 4 nodes/step, 8 steps.
    for (int g = 0; g < 8; ++g) {
        int Lr = wave * 32 + g * 4 + quad;
        int node = row0 + Lr;
        float s[8] = {0.f, 0.f, 0.f, 0.f, 0.f, 0.f, 0.f, 0.f};
        if (node < N_NODES) {
            const int* idx = nbr + node * DEG;
#pragma unroll
            for (int d = 0; d < DEG; ++d) {
                int nb = idx[d];
                u16x8 v = *(const u16x8*)(fb + nb * FDIM + colb);
#pragma unroll
                for (int j = 0; j < 8; ++j) s[j] += bf2f(v[j]);
            }
        }
        u16x8 o;
#pragma unroll
        for (int j = 0; j < 8; ++j) o[j] = f2bf(s[j] * 0.0625f);
        *(u16x8*)(&Agg[Lr][colb]) = o;
    }
    __syncthreads();

    // Phase 2: MFMA. kc 0-3: A self frags direct from global fb; kc 4-7: from LDS Agg.
    f32x4 acc[2][8] = {};
#pragma unroll
    for (int kc = 0; kc < 8; ++kc) {
        bf16x8 a[2], b[8];
#pragma unroll
        for (int mt = 0; mt < 2; ++mt) {
            int lr = wave * 32 + mt * 16 + m16;
            if (kc < 4) {
                int grow = row0 + lr;
                bf16x8 z = {};
                a[mt] = (grow < N_NODES) ? *(const bf16x8*)(fb + grow * FDIM + kc * 32 + quad * 8) : z;
            } else {
                a[mt] = *(const bf16x8*)(&Agg[lr][(kc - 4) * 32 + quad * 8]);
            }
        }
#pragma unroll
        for (int nt = 0; nt < 8; ++nt)
            b[nt] = *(const bf16x8*)(w1T + (nt * 16 + m16) * 256 + kc * 32 + quad * 8);
#pragma unroll
        for (int mt = 0; mt < 2; ++mt)
#pragma unroll
            for (int nt = 0; nt < 8; ++nt)
                acc[mt][nt] = __builtin_amdgcn_mfma_f32_16x16x32_bf16(a[mt], b[nt], acc[mt][nt], 0, 0, 0);
    }

    // Epilogue: row = quad*4 + reg (within 16-tile), col = nt*16 + m16
#pragma unroll
    for (int mt = 0; mt < 2; ++mt) {
        int rbase = row0 + wave * 32 + mt * 16 + quad * 4;
#pragma unroll
        for (int reg = 0; reg < 4; ++reg) {
            int grow = rbase + reg;
            if (grow >= N_NODES) continue;
#pragma unroll
            for (int nt = 0; nt < 8; ++nt)
                h1[grow * HDIM + nt * 16 + m16] = f2bf(acc[mt][nt][reg]);
        }
    }
}

// Layer 2 fused: block = 256 threads, 64 batch rows. B=8192 -> 128 blocks exactly.
__global__ __launch_bounds__(256)
void g2_fused(const unsigned short* __restrict__ h1, const unsigned short* __restrict__ w2T,
              const int* __restrict__ nbr, const int* __restrict__ nodes,
              float* __restrict__ out) {
    __shared__ unsigned short X2[64][264];
    const int t = threadIdx.x, wave = t >> 6, lane = t & 63;
    const int m16 = lane & 15, quad = lane >> 4;
    const int b0 = blockIdx.x * 64;
    const int colb = m16 * 8;

    // Phase 1: self copy + neighbor mean into X2
    for (int g = 0; g < 4; ++g) {
        int Ln = wave * 16 + g * 4 + quad;
        int node = nodes[b0 + Ln];
        *(u16x8*)(&X2[Ln][colb]) = *(const u16x8*)(h1 + node * HDIM + colb);
        const int* idx = nbr + node * DEG;
        float s[8] = {0.f, 0.f, 0.f, 0.f, 0.f, 0.f, 0.f, 0.f};
#pragma unroll
        for (int d = 0; d < DEG; ++d) {
            int nb = idx[d];
            u16x8 v = *(const u16x8*)(h1 + nb * HDIM + colb);
#pragma unroll
            for (int j = 0; j < 8; ++j) s[j] += bf2f(v[j]);
        }
        u16x8 o;
#pragma unroll
        for (int j = 0; j < 8; ++j) o[j] = f2bf(s[j] * 0.0625f);
        *(u16x8*)(&X2[Ln][128 + colb]) = o;
    }
    __syncthreads();

    // Phase 2: each wave computes 16 rows x 128 cols
    f32x4 acc[8] = {};
#pragma unroll
    for (int kc = 0; kc < 8; ++kc) {
        bf16x8 a = *(const bf16x8*)(&X2[wave * 16 + m16][kc * 32 + quad * 8]);
#pragma unroll
        for (int nt = 0; nt < 8; ++nt) {
            bf16x8 b = *(const bf16x8*)(w2T + (nt * 16 + m16) * 256 + kc * 32 + quad * 8);
            acc[nt] = __builtin_amdgcn_mfma_f32_16x16x32_bf16(a, b, acc[nt], 0, 0, 0);
        }
    }

#pragma unroll
    for (int nt = 0; nt < 8; ++nt)
#pragma unroll
        for (int reg = 0; reg < 4; ++reg) {
            int row = b0 + wave * 16 + quad * 4 + reg;
            out[row * 128 + nt * 16 + m16] = acc[nt][reg];
        }
}

extern "C" void kernel_launch(void* const* d_in, const int* in_sizes, int n_in,
                              void* d_out, int out_size, void* d_ws, size_t ws_size,
                              hipStream_t stream) {
    const float* feat  = (const float*)d_in[0];
    const float* w1    = (const float*)d_in[1];
    const float* w2    = (const float*)d_in[2];
    const int*   nbr   = (const int*)d_in[3];
    const int*   nodes = (const int*)d_in[4];
    float* out = (float*)d_out;

    char* ws = (char*)d_ws;
    unsigned short* fb  = (unsigned short*)ws;                       // N*128 bf16 = 25.6 MB
    unsigned short* h1  = (unsigned short*)(ws + 25600000);          // N*128 bf16 = 25.6 MB
    unsigned short* w1T = (unsigned short*)(ws + 51200000);          // 64 KB
    unsigned short* w2T = (unsigned short*)(ws + 51265536);          // 64 KB

    prep_feat<<<6250, 256, 0, stream>>>(feat, fb);
    prep_w<<<16, 256, 0, stream>>>(w1, w2, w1T, w2T);
    g1_fused<<<(N_NODES + 127) / 128, 256, 0, stream>>>(fb, w1T, nbr, h1);
    g2_fused<<<B_NODES / 64, 256, 0, stream>>>(h1, w2T, nbr, nodes, out);
}

// Round 3
// 185.616 us; speedup vs baseline: 1.1162x; 1.1041x over previous
//
#include <hip/hip_runtime.h>

// GraphSage on MI355X — round 3.
//   prep  : feat fp32 [N,128] -> f8 (fp8 e4m3, gather source, 128 B/row)
//           + w1,w2 fp32 [256,128] -> w1T,w2T bf16 [n][k]
//   k1_agg: standalone high-occupancy gather: agg[N,128] bf16 = mean_d f8[nbr[n][d]]
//           (fp8 halves gather bytes: 410 -> 205 MB logical; fp32 accumulate)
//   g1    : h1[N,128] bf16 = [feat(bf16 in-reg) | agg] @ w1T   (pure MFMA, no LDS)
//   g2    : out[B,128] fp32 = [h1[node] | mean h1[nbr]] @ w2T  (fused, 64 rows/block)

#define N_NODES 100000
#define DEG     16
#define FDIM    128
#define HDIM    128
#define B_NODES 8192

typedef __attribute__((ext_vector_type(8))) short bf16x8;
typedef __attribute__((ext_vector_type(8))) unsigned short u16x8;
typedef __attribute__((ext_vector_type(4))) float f32x4;
typedef __attribute__((ext_vector_type(2))) float f32x2;

static __device__ __forceinline__ unsigned short f2bf(float f) {
    union { float f; unsigned u; } v; v.f = f;
    unsigned r = v.u + 0x7fff + ((v.u >> 16) & 1);   // RNE
    return (unsigned short)(r >> 16);
}
static __device__ __forceinline__ float bf2f(unsigned short b) {
    union { unsigned u; float f; } v; v.u = ((unsigned)b) << 16;
    return v.f;
}

// blocks 0..6249: cast feat -> f8. blocks 6250..6265: transpose+cast w1/w2.
__global__ __launch_bounds__(256)
void prep(const float* __restrict__ feat, const float* __restrict__ w1,
          const float* __restrict__ w2, unsigned char* __restrict__ f8,
          unsigned short* __restrict__ w1T, unsigned short* __restrict__ w2T) {
    if (blockIdx.x < 6250) {
        long e = ((long)blockIdx.x * 256 + threadIdx.x) * 8;   // 6250*256*8 = 12.8M exact
        float4 v0 = *(const float4*)(feat + e);
        float4 v1 = *(const float4*)(feat + e + 4);
        int p0 = 0, p1 = 0;
        p0 = __builtin_amdgcn_cvt_pk_fp8_f32(v0.x, v0.y, p0, false);
        p0 = __builtin_amdgcn_cvt_pk_fp8_f32(v0.z, v0.w, p0, true);
        p1 = __builtin_amdgcn_cvt_pk_fp8_f32(v1.x, v1.y, p1, false);
        p1 = __builtin_amdgcn_cvt_pk_fp8_f32(v1.z, v1.w, p1, true);
        uint2 o; o.x = (unsigned)p0; o.y = (unsigned)p1;
        *(uint2*)(f8 + e) = o;
    } else {
        int bid = blockIdx.x - 6250;
        const float* w = (bid < 8) ? w1 : w2;
        unsigned short* wT = (bid < 8) ? w1T : w2T;
        int kb = (bid & 7) * 32;
        int n = threadIdx.x & 127, dk = threadIdx.x >> 7;
#pragma unroll
        for (int i = 0; i < 16; ++i) {
            int k = kb + dk * 16 + i;
            wT[n * 256 + k] = f2bf(w[k * 128 + n]);   // read coalesced over n
        }
    }
}

// 16 nodes per 256-thread block; 16 lanes per node, 8 B fp8 per lane per neighbor.
__global__ __launch_bounds__(256)
void k1_agg(const unsigned char* __restrict__ f8, const int* __restrict__ nbr,
            unsigned short* __restrict__ agg) {
    const int t = threadIdx.x;
    const int node = blockIdx.x * 16 + (t >> 4);      // 6250*16 = 100000 exact
    const int cg = (t & 15) * 8;
    const int* idx = nbr + node * DEG;
    float s[8] = {0.f, 0.f, 0.f, 0.f, 0.f, 0.f, 0.f, 0.f};
#pragma unroll
    for (int d = 0; d < DEG; ++d) {
        int nb = idx[d];
        uint2 v = *(const uint2*)(f8 + (long)nb * FDIM + cg);
        f32x2 a0 = __builtin_amdgcn_cvt_pk_f32_fp8((int)v.x, false);
        f32x2 a1 = __builtin_amdgcn_cvt_pk_f32_fp8((int)v.x, true);
        f32x2 a2 = __builtin_amdgcn_cvt_pk_f32_fp8((int)v.y, false);
        f32x2 a3 = __builtin_amdgcn_cvt_pk_f32_fp8((int)v.y, true);
        s[0] += a0[0]; s[1] += a0[1]; s[2] += a1[0]; s[3] += a1[1];
        s[4] += a2[0]; s[5] += a2[1]; s[6] += a3[0]; s[7] += a3[1];
    }
    u16x8 o;
#pragma unroll
    for (int j = 0; j < 8; ++j) o[j] = f2bf(s[j] * 0.0625f);
    *(u16x8*)(agg + node * 128 + cg) = o;
}

// Pure GEMM: h1 = [feat | agg] @ w1T. 128 rows/block, no LDS.
__global__ __launch_bounds__(256)
void g1(const float* __restrict__ feat, const unsigned short* __restrict__ agg,
        const unsigned short* __restrict__ w1T, unsigned short* __restrict__ h1) {
    const int t = threadIdx.x, wave = t >> 6, lane = t & 63;
    const int m16 = lane & 15, quad = lane >> 4;
    const int row0 = blockIdx.x * 128;

    f32x4 acc[2][8] = {};
#pragma unroll
    for (int kc = 0; kc < 8; ++kc) {
        bf16x8 a[2], b[8];
#pragma unroll
        for (int mt = 0; mt < 2; ++mt) {
            int grow = row0 + wave * 32 + mt * 16 + m16;
            bf16x8 z = {};
            if (grow >= N_NODES) {
                a[mt] = z;
            } else if (kc < 4) {
                const float* p = feat + (long)grow * 128 + kc * 32 + quad * 8;
                float4 u0 = *(const float4*)p;
                float4 u1 = *(const float4*)(p + 4);
                bf16x8 c;
                c[0] = (short)f2bf(u0.x); c[1] = (short)f2bf(u0.y);
                c[2] = (short)f2bf(u0.z); c[3] = (short)f2bf(u0.w);
                c[4] = (short)f2bf(u1.x); c[5] = (short)f2bf(u1.y);
                c[6] = (short)f2bf(u1.z); c[7] = (short)f2bf(u1.w);
                a[mt] = c;
            } else {
                a[mt] = *(const bf16x8*)(agg + (long)grow * 128 + (kc - 4) * 32 + quad * 8);
            }
        }
#pragma unroll
        for (int nt = 0; nt < 8; ++nt)
            b[nt] = *(const bf16x8*)(w1T + (nt * 16 + m16) * 256 + kc * 32 + quad * 8);
#pragma unroll
        for (int mt = 0; mt < 2; ++mt)
#pragma unroll
            for (int nt = 0; nt < 8; ++nt)
                acc[mt][nt] = __builtin_amdgcn_mfma_f32_16x16x32_bf16(a[mt], b[nt], acc[mt][nt], 0, 0, 0);
    }

    // C layout: row = quad*4 + reg, col = nt*16 + m16
#pragma unroll
    for (int mt = 0; mt < 2; ++mt) {
        int rbase = row0 + wave * 32 + mt * 16 + quad * 4;
#pragma unroll
        for (int reg = 0; reg < 4; ++reg) {
            int grow = rbase + reg;
            if (grow >= N_NODES) continue;
#pragma unroll
            for (int nt = 0; nt < 8; ++nt)
                h1[grow * HDIM + nt * 16 + m16] = f2bf(acc[mt][nt][reg]);
        }
    }
}

// Layer 2 fused: 64 batch rows per 256-thread block. 128 blocks exact.
__global__ __launch_bounds__(256)
void g2_fused(const unsigned short* __restrict__ h1, const unsigned short* __restrict__ w2T,
              const int* __restrict__ nbr, const int* __restrict__ nodes,
              float* __restrict__ out) {
    __shared__ unsigned short X2[64][264];
    const int t = threadIdx.x, wave = t >> 6, lane = t & 63;
    const int m16 = lane & 15, quad = lane >> 4;
    const int b0 = blockIdx.x * 64;
    const int colb = m16 * 8;

    for (int g = 0; g < 4; ++g) {
        int Ln = wave * 16 + g * 4 + quad;
        int node = nodes[b0 + Ln];
        *(u16x8*)(&X2[Ln][colb]) = *(const u16x8*)(h1 + node * HDIM + colb);
        const int* idx = nbr + node * DEG;
        float s[8] = {0.f, 0.f, 0.f, 0.f, 0.f, 0.f, 0.f, 0.f};
#pragma unroll
        for (int d = 0; d < DEG; ++d) {
            int nb = idx[d];
            u16x8 v = *(const u16x8*)(h1 + nb * HDIM + colb);
#pragma unroll
            for (int j = 0; j < 8; ++j) s[j] += bf2f(v[j]);
        }
        u16x8 o;
#pragma unroll
        for (int j = 0; j < 8; ++j) o[j] = f2bf(s[j] * 0.0625f);
        *(u16x8*)(&X2[Ln][128 + colb]) = o;
    }
    __syncthreads();

    f32x4 acc[8] = {};
#pragma unroll
    for (int kc = 0; kc < 8; ++kc) {
        bf16x8 a = *(const bf16x8*)(&X2[wave * 16 + m16][kc * 32 + quad * 8]);
#pragma unroll
        for (int nt = 0; nt < 8; ++nt) {
            bf16x8 b = *(const bf16x8*)(w2T + (nt * 16 + m16) * 256 + kc * 32 + quad * 8);
            acc[nt] = __builtin_amdgcn_mfma_f32_16x16x32_bf16(a, b, acc[nt], 0, 0, 0);
        }
    }

#pragma unroll
    for (int nt = 0; nt < 8; ++nt)
#pragma unroll
        for (int reg = 0; reg < 4; ++reg) {
            int row = b0 + wave * 16 + quad * 4 + reg;
            out[row * 128 + nt * 16 + m16] = acc[nt][reg];
        }
}

extern "C" void kernel_launch(void* const* d_in, const int* in_sizes, int n_in,
                              void* d_out, int out_size, void* d_ws, size_t ws_size,
                              hipStream_t stream) {
    const float* feat  = (const float*)d_in[0];
    const float* w1    = (const float*)d_in[1];
    const float* w2    = (const float*)d_in[2];
    const int*   nbr   = (const int*)d_in[3];
    const int*   nodes = (const int*)d_in[4];
    float* out = (float*)d_out;

    char* ws = (char*)d_ws;
    unsigned char*  f8  = (unsigned char*)ws;                        // N*128 fp8  = 12.8 MB
    unsigned short* agg = (unsigned short*)(ws + 12800000);          // N*128 bf16 = 25.6 MB
    unsigned short* h1  = (unsigned short*)(ws + 38400000);          // N*128 bf16 = 25.6 MB
    unsigned short* w1T = (unsigned short*)(ws + 64000000);          // 64 KB
    unsigned short* w2T = (unsigned short*)(ws + 64065536);          // 64 KB

    prep<<<6266, 256, 0, stream>>>(feat, w1, w2, f8, w1T, w2T);
    k1_agg<<<6250, 256, 0, stream>>>(f8, nbr, agg);
    g1<<<(N_NODES + 127) / 128, 256, 0, stream>>>(feat, agg, w1T, h1);
    g2_fused<<<B_NODES / 64, 256, 0, stream>>>(h1, w2T, nbr, nodes, out);
}